// Round 10
// baseline (303.577 us; speedup 1.0000x reference)
//
#include <hip/hip_runtime.h>
#include <hip/hip_bf16.h>
#include <stdint.h>

// ---------------------------------------------------------------------------
// CharToWord v10: bidirectional char-GRU + attention pooling.
// v9 post-mortem: occupancy (v6), VALU diet (v8), dual-chain ILP (v9) all
// left gru time invariant at ~4500 cy/block-step (8x the pipe model).
// The unremoved structural cost: __syncthreads() drains vmcnt(0) before
// s_barrier (m97 barrier-drain), so every step serially waits for the
// global hout store to commit (~400-1000cy) and attn's prefetch dies at
// its barrier. v10 = v8 base + raw lgkmcnt-only barriers (LDS visibility
// needs only lgkmcnt; stores/loads float across) in gru + attn loops.
// ---------------------------------------------------------------------------

typedef unsigned short u16;
typedef float f32x4 __attribute__((ext_vector_type(4)));
typedef __bf16 bf16x8 __attribute__((ext_vector_type(8)));

#if __has_builtin(__builtin_amdgcn_exp2f)
#define EXP2F(x) __builtin_amdgcn_exp2f(x)
#else
#define EXP2F(x) exp2f(x)
#endif
#if __has_builtin(__builtin_amdgcn_rcpf)
#define RCPF(x) __builtin_amdgcn_rcpf(x)
#else
#define RCPF(x) (1.0f / (x))
#endif

#define LOG2E 1.4426950408889634f

__device__ __forceinline__ u16 f2b(float f) {
  uint32_t u = __builtin_bit_cast(uint32_t, f);
  u = u + 0x7FFFu + ((u >> 16) & 1u);
  return (u16)(u >> 16);
}
__device__ __forceinline__ float b2f(u16 s) {
  uint32_t u = ((uint32_t)s) << 16;
  return __builtin_bit_cast(float, u);
}
__device__ __forceinline__ float fast_tanh(float x) {
  return 1.0f - 2.0f * RCPF(EXP2F(2.0f * LOG2E * x) + 1.0f);
}
__device__ __forceinline__ uint32_t cvtpk(float a, float b) {
  uint32_t r;
  asm("v_cvt_pk_bf16_f32 %0, %1, %2" : "=v"(r) : "v"(a), "v"(b));
  return r;
}
// Barrier with LDS-only drain: s_waitcnt lgkmcnt(0) + raw s_barrier.
// Global stores/loads stay in flight across it (no vmcnt(0) drain).
// sched_barrier(0) fences prevent LDS op hoisting (rule #18).
__device__ __forceinline__ void bar_lds() {
  __builtin_amdgcn_sched_barrier(0);
  asm volatile("s_waitcnt lgkmcnt(0)" ::: "memory");
  __builtin_amdgcn_s_barrier();
  __builtin_amdgcn_sched_barrier(0);
}

// ---------------------------------------------------------------------------
// prep: grid 448 x 256 (identical to v8)
// ---------------------------------------------------------------------------
__global__ void prep_kernel(
    const float* __restrict__ emb,
    const float* __restrict__ wih_f, const float* __restrict__ bih_f,
    const float* __restrict__ wih_b, const float* __restrict__ bih_b,
    const float* __restrict__ bhh_f, const float* __restrict__ bhh_b,
    const float* __restrict__ whh_f_in, const float* __restrict__ whh_b_in,
    const float* __restrict__ wp_in,
    float* __restrict__ xpf_f, float* __restrict__ xpf_b,
    u16* __restrict__ whhf, u16* __restrict__ whhb, u16* __restrict__ wpf) {
  int gid = blockIdx.x * 256 + threadIdx.x;
  if (blockIdx.x < 384) {
    int e = gid;                    // 0..98303
    int d = (e >= 49152) ? 1 : 0;
    int r = e - d * 49152;
    int j = r & 3;
    int e2 = r >> 2;                // 12288
    int cls = e2 % 3;
    int e3 = e2 / 3;                // 4096
    int grp = e3 & 3;
    int e4 = e3 >> 2;               // 1024
    int wv = e4 & 7;
    int c = e4 >> 3;                // 128
    int row = cls * 128 + wv * 16 + grp * 4 + j;
    const float* wih = d ? wih_b : wih_f;
    const float* bih = d ? bih_b : bih_f;
    const float* bhh = d ? bhh_b : bhh_f;
    const float4* e4p = (const float4*)(emb + c * 64);
    const float4* w4p = (const float4*)(wih + row * 64);
    float s = 0.f;
#pragma unroll
    for (int q = 0; q < 16; q++) {
      float4 a = e4p[q], b = w4p[q];
      s += a.x * b.x + a.y * b.y + a.z * b.z + a.w * b.w;
    }
    s += bih[row];
    float scale;
    if (cls < 2) {
      s += bhh[row];
      scale = -LOG2E;
    } else {
      scale = 2.0f * LOG2E;
    }
    (d ? xpf_b : xpf_f)[r] = s * scale;
  } else if (blockIdx.x < 432) {
    int idx = gid - 384 * 256;  // 0..12287
    int d = (idx >= 6144) ? 1 : 0;
    int r = idx - d * 6144;
    int lane = r & 63, kt = (r >> 6) & 3, nt = r >> 8;
    float scale = (nt < 16) ? -LOG2E : 2.0f * LOG2E;  // cls = nt>>3
    int n = nt * 16 + (lane & 15);
    int k0 = kt * 32 + (lane >> 4) * 8;
    const float* w = d ? whh_b_in : whh_f_in;
    u16* o = (d ? whhb : whhf) + r * 8;
    for (int j = 0; j < 8; j++) o[j] = f2b(w[n * 128 + k0 + j] * scale);
  } else {
    int idx = gid - 432 * 256;  // 0..4095
    if (idx < 4096) {
      int lane = idx & 63, kt = (idx >> 6) & 7, nt = idx >> 9;
      int n = nt * 16 + (lane & 15);
      int k0 = kt * 32 + (lane >> 4) * 8;
      u16* o = wpf + idx * 8;
      for (int j = 0; j < 8; j++) o[j] = f2b(wp_in[n * 256 + k0 + j]);
    }
  }
}

// ---------------------------------------------------------------------------
// counting sort by length (bins 1..20); c0 = pad-position attention score.
// ---------------------------------------------------------------------------
__global__ void sort_zero(int* __restrict__ bins) {
  if (threadIdx.x < 32) bins[threadIdx.x] = 0;
}
__global__ void sort_hist(const int* __restrict__ lens, int* __restrict__ bins) {
  __shared__ int hcnt[32];
  int tid = threadIdx.x;
  if (tid < 32) hcnt[tid] = 0;
  __syncthreads();
  int gid = blockIdx.x * 256 + tid;
  int l = lens[gid] & 31;
  atomicAdd(&hcnt[l], 1);
  __syncthreads();
  if (tid < 32 && hcnt[tid]) atomicAdd(&bins[tid], hcnt[tid]);
}
__global__ void sort_scan(const int* __restrict__ bins, int* __restrict__ offsw,
                          const float* __restrict__ bp,
                          const float* __restrict__ ctx,
                          float* __restrict__ c0out) {
  if (threadIdx.x == 0 && blockIdx.x == 0) {
    int off = 0;
    for (int l = 0; l < 32; l++) {
      offsw[l] = off;
      off += bins[l];
    }
    float c0 = 0.f;
    for (int c = 0; c < 128; c++) c0 += fast_tanh(bp[c]) * ctx[c];
    *c0out = c0;
  }
}
__global__ void sort_scat(const int* __restrict__ lens, int* __restrict__ offsw,
                          int* __restrict__ perm) {
  __shared__ int lcnt[32];
  __shared__ int lbase[32];
  int tid = threadIdx.x;
  if (tid < 32) lcnt[tid] = 0;
  __syncthreads();
  int gid = blockIdx.x * 256 + tid;
  int l = lens[gid] & 31;
  int lr = atomicAdd(&lcnt[l], 1);
  __syncthreads();
  if (tid < 32) lbase[tid] = lcnt[tid] ? atomicAdd(&offsw[tid], lcnt[tid]) : 0;
  __syncthreads();
  perm[lbase[l] + lr] = gid;
}

// ---------------------------------------------------------------------------
// gru: grid 2*nbd x 512. bid parity = direction; 16 sorted words/block.
// Operand-swapped: C[gate][word] = mfma(Whh'_regs, h_LDS). Thread (wv,ln):
// word = ln&15, hids = wv*16 + (ln>>4)*4 + r (4 consecutive, one frag slot).
// h_s frag-linear double-buffered; ONE lgkm-only barrier per step. LPT.
// ---------------------------------------------------------------------------
__global__ __launch_bounds__(512, 4) void gru_kernel(
    const int* __restrict__ chars, const int* __restrict__ lens,
    const int* __restrict__ perm,
    const float* __restrict__ xpf_f, const float* __restrict__ xpf_b,
    const u16* __restrict__ whhf, const u16* __restrict__ whhb,
    const float* __restrict__ bhh_f, const float* __restrict__ bhh_b,
    u16* __restrict__ hf, u16* __restrict__ hb, int word_off, int nbd) {
  const int bid = blockIdx.x;
  const int dir = bid & 1;
  const int wg = nbd - 1 - (bid >> 1);  // longest-first
  const int tid = threadIdx.x;

  __shared__ int perm_s[16];
  __shared__ unsigned char lens_s[16];
  __shared__ int coff_s[320];      // c*384 (xp float offset), pre-remapped t
  __shared__ u16 h_s[2][2048];     // frag-linear: (kt*64+lane)*8 + j

  if (tid < 16) {
    int p = perm[word_off + wg * 16 + tid];
    perm_s[tid] = p;
    lens_s[tid] = (unsigned char)lens[p];
  }
  for (int i = tid; i < 1024; i += 512) ((uint32_t*)h_s)[i] = 0u;
  __syncthreads();
  for (int i = tid; i < 320; i += 512) {
    int w = i & 15, s = i >> 4;
    int L = lens_s[w];
    int t = dir ? ((s < L) ? (L - 1 - s) : s) : s;
    coff_s[s * 16 + w] = chars[perm_s[w] * 20 + t] * 384;
  }

  const float* xp = dir ? xpf_b : xpf_f;
  const u16* whh = dir ? whhb : whhf;
  const float* bhh = dir ? bhh_b : bhh_f;
  u16* hout = (dir ? hb : hf) + (size_t)wg * 16 * 2560;

  const int wv = tid >> 6, ln = tid & 63, word = ln & 15, grp = ln >> 4;
  const float* xpt = xp + (wv * 4 + grp) * 12;

  // Whh' A-fragments (pre-scaled): 48 VGPRs, once per block
  bf16x8 Wf[3][4];
#pragma unroll
  for (int cls = 0; cls < 3; cls++) {
    int nt = cls * 8 + wv;
#pragma unroll
    for (int kt = 0; kt < 4; kt++)
      Wf[cls][kt] = *(const bf16x8*)(whh + (((nt * 4 + kt) * 64 + ln) << 3));
  }
  // bhh_n (scaled 2log2e) for this thread's 4 hids
  float4 bhn = *(const float4*)(bhh + 256 + wv * 16 + grp * 4);
  bhn.x *= 2.0f * LOG2E; bhn.y *= 2.0f * LOG2E;
  bhn.z *= 2.0f * LOG2E; bhn.w *= 2.0f * LOG2E;

  __syncthreads();  // coff_s + h_s zero ready

  const int Lmax = lens_s[15];  // sorted ascending within block

  // h_s write offset (bytes within a buffer): v8-verified mapping
  const int hw_off =
      (((wv >> 1) * 64) + (word | (((wv & 1) * 2 + (grp >> 1)) << 4))) * 16 +
      (grp & 1) * 8;
  // store phase: thread -> (word swd, 4-hid slice k4)
  const int swd = tid >> 5;
  const int k4 = (tid & 31) << 2;
  const int sL = lens_s[swd];
  const int hs_off =
      (((k4 >> 5) * 64) + (swd | (((k4 >> 3) & 3) << 4))) * 16 + (k4 & 7) * 2;

  char* hsb = (char*)h_s;

  float hreg[4] = {0.f, 0.f, 0.f, 0.f};
  f32x4 xA0, xA1, xA2, xB0, xB1, xB2;
  {
    int off = coff_s[word];
    xA0 = *(const f32x4*)(xpt + off);
    xA1 = *(const f32x4*)(xpt + off + 4);
    xA2 = *(const f32x4*)(xpt + off + 8);
  }

#define GSTEP(S, PAR, XC0, XC1, XC2, XN0, XN1, XN2)                           \
  {                                                                           \
    if ((S) + 1 < Lmax) {                                                     \
      int off = coff_s[((S) + 1) * 16 + word];                                \
      XN0 = *(const f32x4*)(xpt + off);                                       \
      XN1 = *(const f32x4*)(xpt + off + 4);                                   \
      XN2 = *(const f32x4*)(xpt + off + 8);                                   \
    }                                                                         \
    f32x4 a0 = (f32x4){0.f, 0.f, 0.f, 0.f};                                   \
    f32x4 a1 = (f32x4){0.f, 0.f, 0.f, 0.f};                                   \
    f32x4 a2 = (f32x4){bhn.x, bhn.y, bhn.z, bhn.w};                           \
    _Pragma("unroll")                                                         \
    for (int kt = 0; kt < 4; kt++) {                                          \
      bf16x8 Hf =                                                             \
          *(const bf16x8*)(hsb + (PAR) * 4096 + ((kt * 64 + ln) << 4));       \
      a0 = __builtin_amdgcn_mfma_f32_16x16x32_bf16(Wf[0][kt], Hf, a0, 0, 0, 0); \
      a1 = __builtin_amdgcn_mfma_f32_16x16x32_bf16(Wf[1][kt], Hf, a1, 0, 0, 0); \
      a2 = __builtin_amdgcn_mfma_f32_16x16x32_bf16(Wf[2][kt], Hf, a2, 0, 0, 0); \
    }                                                                         \
    _Pragma("unroll")                                                         \
    for (int r = 0; r < 4; r++) {                                             \
      float rr = RCPF(1.0f + EXP2F(XC0[r] + a0[r]));                          \
      float zz = RCPF(1.0f + EXP2F(XC1[r] + a1[r]));                          \
      float na = fmaf(rr, a2[r], XC2[r]);                                     \
      float nn = fmaf(-2.0f, RCPF(EXP2F(na) + 1.0f), 1.0f);                   \
      hreg[r] = fmaf(zz, hreg[r] - nn, nn);                                   \
    }                                                                         \
    {                                                                         \
      uint2 pk = make_uint2(cvtpk(hreg[0], hreg[1]), cvtpk(hreg[2], hreg[3]));\
      *(uint2*)(hsb + ((PAR) ^ 1) * 4096 + hw_off) = pk;                      \
    }                                                                         \
    bar_lds();                                                                \
    if ((S) < sL) {                                                           \
      int tdst = dir ? (sL - 1 - (S)) : (S);                                  \
      uint2 v = *(const uint2*)(hsb + ((PAR) ^ 1) * 4096 + hs_off);           \
      *(uint2*)(hout + ((size_t)swd * 20 + tdst) * 128 + k4) = v;             \
    }                                                                         \
  }

  for (int s = 0; s < Lmax; s += 2) {
    GSTEP(s, 0, xA0, xA1, xA2, xB0, xB1, xB2);
    if (s + 1 < Lmax) GSTEP(s + 1, 1, xB0, xB1, xB2, xA0, xA1, xA2);
  }
#undef GSTEP
}

// ---------------------------------------------------------------------------
// attn: grid nbA x 256. 16 sorted words/block, 16 threads/word (facc[16]).
// lgkm-only barriers -> vn prefetch actually spans the MFMA phase now.
// Online softmax over valid t + pad mass (20-L)*e^{c0-mrun}. LPT order.
// ---------------------------------------------------------------------------
__global__ __launch_bounds__(256, 2) void attn_kernel(
    const u16* __restrict__ hf, const u16* __restrict__ hb,
    const u16* __restrict__ wpf,
    const float* __restrict__ bp, const float* __restrict__ ctx,
    const int* __restrict__ perm, const int* __restrict__ lens,
    const float* __restrict__ c0p,
    float* __restrict__ out, int word_off) {
  const int blk = gridDim.x - 1 - blockIdx.x;  // longest-first
  const int lw0 = blk * 16;

  __shared__ u16 ot_s[4096];       // 8 KiB: Out_t frag layout (16x256)
  __shared__ float part_s[4][16];
  __shared__ int perm_s[16];
  __shared__ unsigned char lens_s[16];

  const int tid = threadIdx.x;
  const int wv = tid >> 6, ln = tid & 63, col = ln & 15, grp = ln >> 4;
  const int sw = tid >> 4;   // this thread's word (16 threads per word)
  const int seg = tid & 15;  // 16-dim segment of the 256-dim output

  if (tid < 16) {
    int p = perm[word_off + lw0 + tid];
    perm_s[tid] = p;
    lens_s[tid] = (unsigned char)lens[p];
  }
  __syncthreads();
  const int Lmax = lens_s[15];  // sorted ascending within block
  const int Lw = lens_s[sw];

  float bpv[2], ctxv[2];
#pragma unroll
  for (int n = 0; n < 2; n++) {
    int nt = wv + n * 4;
    bpv[n] = bp[nt * 16 + col];
    ctxv[n] = ctx[nt * 16 + col];
  }

  float facc[16];
#pragma unroll
  for (int i = 0; i < 16; i++) facc[i] = 0.f;
  float mrun = -3.0e38f, drun = 0.f;

  // seg 0..7 -> hf dims [seg*16,+16); seg 8..15 -> hb dims [(seg-8)*16,+16)
  const u16* srcbase =
      ((seg < 8) ? hf : hb) + (size_t)(lw0 + sw) * 2560 + (seg & 7) * 16;

  uint4 vn[2];
#pragma unroll
  for (int q = 0; q < 2; q++) vn[q] = *(const uint4*)(srcbase + q * 8);

  for (int t = 0; t < Lmax; t++) {
    uint4 v[2];
    v[0] = vn[0];
    v[1] = vn[1];

    // stage Out_t into frag layout: k = seg*16 + q*8
#pragma unroll
    for (int q = 0; q < 2; q++) {
      int idx = seg * 2 + q;           // k>>3, 0..31
      int kt = idx >> 2;               // k>>5
      int lane_a = sw | ((idx & 3) << 4);
      *(uint4*)(ot_s + ((kt * 64 + lane_a) << 3)) = v[q];
    }
    // prefetch next t (now genuinely hidden: barrier no longer drains vmcnt)
    if (t + 1 < Lmax) {
      const u16* src = srcbase + (t + 1) * 128;
#pragma unroll
      for (int q = 0; q < 2; q++) vn[q] = *(const uint4*)(src + q * 8);
    }
    bar_lds();

    // proj = Out_t @ Wp^T + bp (Wp frags from L2)
    f32x4 acc[2];
#pragma unroll
    for (int n = 0; n < 2; n++) acc[n] = (f32x4){bpv[n], bpv[n], bpv[n], bpv[n]};

#pragma unroll
    for (int kt = 0; kt < 8; kt++) {
      bf16x8 Af = *(const bf16x8*)(ot_s + ((kt * 64 + ln) << 3));
#pragma unroll
      for (int n = 0; n < 2; n++) {
        int nt = wv + n * 4;
        bf16x8 Bf = *(const bf16x8*)(wpf + (((nt * 8 + kt) * 64 + ln) << 3));
        acc[n] = __builtin_amdgcn_mfma_f32_16x16x32_bf16(Af, Bf, acc[n], 0, 0, 0);
      }
    }

    // score partials: tanh(proj)*ctx summed over cols; words at (grp*4+r)
#pragma unroll
    for (int r = 0; r < 4; r++) {
      float p = fast_tanh(acc[0][r]) * ctxv[0] + fast_tanh(acc[1][r]) * ctxv[1];
      p += __shfl_xor(p, 1, 64);
      p += __shfl_xor(p, 2, 64);
      p += __shfl_xor(p, 4, 64);
      p += __shfl_xor(p, 8, 64);
      if (col == 0) part_s[wv][grp * 4 + r] = p;
    }
    bar_lds();

    float sc = part_s[0][sw] + part_s[1][sw] + part_s[2][sw] + part_s[3][sw];

    if (t < Lw) {
      float mnew = fmaxf(mrun, sc);
      float scale = EXP2F(LOG2E * (mrun - mnew));
      float e = EXP2F(LOG2E * (sc - mnew));
      drun = drun * scale + e;
      mrun = mnew;
#pragma unroll
      for (int q = 0; q < 2; q++) {
        const u16* pv = (const u16*)&v[q];
#pragma unroll
        for (int j = 0; j < 8; j++)
          facc[q * 8 + j] = facc[q * 8 + j] * scale + e * b2f(pv[j]);
      }
    }
  }

  // reference semantics: softmax over all 20 positions; pad rows are zero
  // with constant score c0 -> denominator-only mass.
  drun += (float)(20 - Lw) * EXP2F(LOG2E * (*c0p - mrun));

  float inv = RCPF(drun);
  float* dst = out + (size_t)perm_s[sw] * 256 + seg * 16;
#pragma unroll
  for (int i = 0; i < 4; i++) {
    float4 o = make_float4(facc[i * 4] * inv, facc[i * 4 + 1] * inv,
                           facc[i * 4 + 2] * inv, facc[i * 4 + 3] * inv);
    *(float4*)(dst + i * 4) = o;
  }
}

// ---------------------------------------------------------------------------
extern "C" void kernel_launch(void* const* d_in, const int* in_sizes, int n_in,
                              void* d_out, int out_size, void* d_ws, size_t ws_size,
                              hipStream_t stream) {
  const int* chars = (const int*)d_in[0];
  const int* lens = (const int*)d_in[1];
  const float* emb = (const float*)d_in[2];
  const float* wih_f = (const float*)d_in[3];
  const float* whh_f = (const float*)d_in[4];
  const float* bih_f = (const float*)d_in[5];
  const float* bhh_f = (const float*)d_in[6];
  const float* wih_b = (const float*)d_in[7];
  const float* whh_b = (const float*)d_in[8];
  const float* bih_b = (const float*)d_in[9];
  const float* bhh_b = (const float*)d_in[10];
  const float* wp = (const float*)d_in[11];
  const float* bp = (const float*)d_in[12];
  const float* ctx = (const float*)d_in[13];
  float* outp = (float*)d_out;

  uint8_t* ws = (uint8_t*)d_ws;
  float* xpf_f = (float*)(ws + 0);            // 192 KiB (49152 f32)
  float* xpf_b = (float*)(ws + 196608);       // 192 KiB
  u16* whhf = (u16*)(ws + 393216);            // 96 KiB
  u16* whhb = (u16*)(ws + 491520);            // 96 KiB
  u16* wpf = (u16*)(ws + 589824);             // 64 KiB
  int* bins = (int*)(ws + 655360);            // 128 B
  int* offsw = (int*)(ws + 655488);           // 128 B
  float* c0p = (float*)(ws + 655616);         // 64 B
  int* permp = (int*)(ws + 655680);           // 128 KiB
  const size_t H_OFF = 1048576;

  prep_kernel<<<448, 256, 0, stream>>>(emb, wih_f, bih_f, wih_b, bih_b, bhh_f,
                                       bhh_b, whh_f, whh_b, wp, xpf_f, xpf_b,
                                       whhf, whhb, wpf);
  sort_zero<<<1, 64, 0, stream>>>(bins);
  sort_hist<<<128, 256, 0, stream>>>(lens, bins);
  sort_scan<<<1, 64, 0, stream>>>(bins, offsw, bp, ctx, c0p);
  sort_scat<<<128, 256, 0, stream>>>(lens, offsw, permp);

  const size_t per_word = 20 * 128 * 2 * 2;  // hf+hb bytes per word
  size_t avail = (ws_size > H_OFF) ? (ws_size - H_OFF) : 0;
  int maxw = (int)(avail / per_word) & ~63;
  if (maxw > 32768) maxw = 32768;
  if (maxw < 64) maxw = 64;

  for (int done = 0; done < 32768;) {
    int nw = (32768 - done < maxw) ? (32768 - done) : maxw;
    u16* hfp = (u16*)(ws + H_OFF);
    u16* hbp = hfp + (size_t)nw * 2560;
    int nbd = nw / 16;
    gru_kernel<<<2 * nbd, 512, 0, stream>>>(chars, lens, permp, xpf_f, xpf_b,
                                            whhf, whhb, bhh_f, bhh_b, hfp, hbp,
                                            done, nbd);
    attn_kernel<<<nw / 16, 256, 0, stream>>>(hfp, hbp, wpf, bp, ctx, permp,
                                             lens, c0p, outp, done);
    done += nw;
  }
}

// Round 11
// 278.328 us; speedup vs baseline: 1.0907x; 1.0907x over previous
//
#include <hip/hip_runtime.h>
#include <hip/hip_bf16.h>
#include <stdint.h>

// ---------------------------------------------------------------------------
// CharToWord v11: bidirectional char-GRU + attention pooling.
// v10 post-mortem: lgkm-only barrier = null (drain theory falsified); its
// sched_barrier(0) pinning REGRESSED attn (-27us) -> plain __syncthreads
// everywhere. Budget rederivation: 2216 cy per block-step vs 466 cy MFMA ->
// ~1000 cy fixed per-barrier-step overhead dominates; occupancy/VALU/ILP
// can't change the ratio. v11 amortizes it: 32-word tile (2 m-tiles, one
// unified step), 2x MFMA per barrier, half the blocks+barriers, and the
// store phase reads whole frag slots (ds_read_b128, conflict-free; was the
// 8-way-conflict ds_read_b64 costing ~275 cy/step).
// ---------------------------------------------------------------------------

typedef unsigned short u16;
typedef float f32x4 __attribute__((ext_vector_type(4)));
typedef __bf16 bf16x8 __attribute__((ext_vector_type(8)));

#if __has_builtin(__builtin_amdgcn_exp2f)
#define EXP2F(x) __builtin_amdgcn_exp2f(x)
#else
#define EXP2F(x) exp2f(x)
#endif
#if __has_builtin(__builtin_amdgcn_rcpf)
#define RCPF(x) __builtin_amdgcn_rcpf(x)
#else
#define RCPF(x) (1.0f / (x))
#endif

#define LOG2E 1.4426950408889634f

__device__ __forceinline__ u16 f2b(float f) {
  uint32_t u = __builtin_bit_cast(uint32_t, f);
  u = u + 0x7FFFu + ((u >> 16) & 1u);
  return (u16)(u >> 16);
}
__device__ __forceinline__ float b2f(u16 s) {
  uint32_t u = ((uint32_t)s) << 16;
  return __builtin_bit_cast(float, u);
}
__device__ __forceinline__ float fast_tanh(float x) {
  return 1.0f - 2.0f * RCPF(EXP2F(2.0f * LOG2E * x) + 1.0f);
}
__device__ __forceinline__ uint32_t cvtpk(float a, float b) {
  uint32_t r;
  asm("v_cvt_pk_bf16_f32 %0, %1, %2" : "=v"(r) : "v"(a), "v"(b));
  return r;
}

// ---------------------------------------------------------------------------
// prep: grid 448 x 256 (identical to v8)
// ---------------------------------------------------------------------------
__global__ void prep_kernel(
    const float* __restrict__ emb,
    const float* __restrict__ wih_f, const float* __restrict__ bih_f,
    const float* __restrict__ wih_b, const float* __restrict__ bih_b,
    const float* __restrict__ bhh_f, const float* __restrict__ bhh_b,
    const float* __restrict__ whh_f_in, const float* __restrict__ whh_b_in,
    const float* __restrict__ wp_in,
    float* __restrict__ xpf_f, float* __restrict__ xpf_b,
    u16* __restrict__ whhf, u16* __restrict__ whhb, u16* __restrict__ wpf) {
  int gid = blockIdx.x * 256 + threadIdx.x;
  if (blockIdx.x < 384) {
    int e = gid;                    // 0..98303
    int d = (e >= 49152) ? 1 : 0;
    int r = e - d * 49152;
    int j = r & 3;
    int e2 = r >> 2;                // 12288
    int cls = e2 % 3;
    int e3 = e2 / 3;                // 4096
    int grp = e3 & 3;
    int e4 = e3 >> 2;               // 1024
    int wv = e4 & 7;
    int c = e4 >> 3;                // 128
    int row = cls * 128 + wv * 16 + grp * 4 + j;
    const float* wih = d ? wih_b : wih_f;
    const float* bih = d ? bih_b : bih_f;
    const float* bhh = d ? bhh_b : bhh_f;
    const float4* e4p = (const float4*)(emb + c * 64);
    const float4* w4p = (const float4*)(wih + row * 64);
    float s = 0.f;
#pragma unroll
    for (int q = 0; q < 16; q++) {
      float4 a = e4p[q], b = w4p[q];
      s += a.x * b.x + a.y * b.y + a.z * b.z + a.w * b.w;
    }
    s += bih[row];
    float scale;
    if (cls < 2) {
      s += bhh[row];
      scale = -LOG2E;
    } else {
      scale = 2.0f * LOG2E;
    }
    (d ? xpf_b : xpf_f)[r] = s * scale;
  } else if (blockIdx.x < 432) {
    int idx = gid - 384 * 256;  // 0..12287
    int d = (idx >= 6144) ? 1 : 0;
    int r = idx - d * 6144;
    int lane = r & 63, kt = (r >> 6) & 3, nt = r >> 8;
    float scale = (nt < 16) ? -LOG2E : 2.0f * LOG2E;  // cls = nt>>3
    int n = nt * 16 + (lane & 15);
    int k0 = kt * 32 + (lane >> 4) * 8;
    const float* w = d ? whh_b_in : whh_f_in;
    u16* o = (d ? whhb : whhf) + r * 8;
    for (int j = 0; j < 8; j++) o[j] = f2b(w[n * 128 + k0 + j] * scale);
  } else {
    int idx = gid - 432 * 256;  // 0..4095
    if (idx < 4096) {
      int lane = idx & 63, kt = (idx >> 6) & 7, nt = idx >> 9;
      int n = nt * 16 + (lane & 15);
      int k0 = kt * 32 + (lane >> 4) * 8;
      u16* o = wpf + idx * 8;
      for (int j = 0; j < 8; j++) o[j] = f2b(wp_in[n * 256 + k0 + j]);
    }
  }
}

// ---------------------------------------------------------------------------
// counting sort by length (bins 1..20); c0 = pad-position attention score.
// ---------------------------------------------------------------------------
__global__ void sort_zero(int* __restrict__ bins) {
  if (threadIdx.x < 32) bins[threadIdx.x] = 0;
}
__global__ void sort_hist(const int* __restrict__ lens, int* __restrict__ bins) {
  __shared__ int hcnt[32];
  int tid = threadIdx.x;
  if (tid < 32) hcnt[tid] = 0;
  __syncthreads();
  int gid = blockIdx.x * 256 + tid;
  int l = lens[gid] & 31;
  atomicAdd(&hcnt[l], 1);
  __syncthreads();
  if (tid < 32 && hcnt[tid]) atomicAdd(&bins[tid], hcnt[tid]);
}
__global__ void sort_scan(const int* __restrict__ bins, int* __restrict__ offsw,
                          const float* __restrict__ bp,
                          const float* __restrict__ ctx,
                          float* __restrict__ c0out) {
  if (threadIdx.x == 0 && blockIdx.x == 0) {
    int off = 0;
    for (int l = 0; l < 32; l++) {
      offsw[l] = off;
      off += bins[l];
    }
    float c0 = 0.f;
    for (int c = 0; c < 128; c++) c0 += fast_tanh(bp[c]) * ctx[c];
    *c0out = c0;
  }
}
__global__ void sort_scat(const int* __restrict__ lens, int* __restrict__ offsw,
                          int* __restrict__ perm) {
  __shared__ int lcnt[32];
  __shared__ int lbase[32];
  int tid = threadIdx.x;
  if (tid < 32) lcnt[tid] = 0;
  __syncthreads();
  int gid = blockIdx.x * 256 + tid;
  int l = lens[gid] & 31;
  int lr = atomicAdd(&lcnt[l], 1);
  __syncthreads();
  if (tid < 32) lbase[tid] = lcnt[tid] ? atomicAdd(&offsw[tid], lcnt[tid]) : 0;
  __syncthreads();
  perm[lbase[l] + lr] = gid;
}

// ---------------------------------------------------------------------------
// gru: grid 2*nbd x 512. bid parity = direction; 32 sorted words/block as
// ONE tile (2 m-tiles of 16 words, unified step). Wave wv owns nt-triple
// {cls*8+wv}, shared across m. Thread (wv,ln): words m*16+(ln&15),
// hids wv*16 + (ln>>4)*4 + r. h_s frag-linear [2][2m][4kt][64][16B] dbuf.
// Store: wave wv reads frag slot (m=wv>>2, kt=wv&3) as ds_read_b128 (0
// conflicts) + 1 global_store_dwordx4, per-lane length predication. LPT.
// ---------------------------------------------------------------------------
__global__ __launch_bounds__(512, 4) void gru_kernel(
    const int* __restrict__ chars, const int* __restrict__ lens,
    const int* __restrict__ perm,
    const float* __restrict__ xpf_f, const float* __restrict__ xpf_b,
    const u16* __restrict__ whhf, const u16* __restrict__ whhb,
    const float* __restrict__ bhh_f, const float* __restrict__ bhh_b,
    u16* __restrict__ hf, u16* __restrict__ hb, int word_off, int nbd) {
  const int bid = blockIdx.x;
  const int dir = bid & 1;
  const int wg = nbd - 1 - (bid >> 1);  // longest-first
  const int tid = threadIdx.x;

  __shared__ int perm_s[32];
  __shared__ unsigned char lens_s[32];
  __shared__ int coff_s[640];      // c*384 (xp float offset), pre-remapped t
  __shared__ u16 h_s[2][4096];     // frag-linear: ((m*4+kt)*64+lane)*8 + j

  if (tid < 32) {
    int p = perm[word_off + wg * 32 + tid];
    perm_s[tid] = p;
    lens_s[tid] = (unsigned char)lens[p];
  }
  for (int i = tid; i < 2048; i += 512) ((uint32_t*)h_s)[i] = 0u;
  __syncthreads();
  for (int i = tid; i < 640; i += 512) {
    int w = i & 31, s = i >> 5;
    int L = lens_s[w];
    int t = dir ? ((s < L) ? (L - 1 - s) : s) : s;
    coff_s[s * 32 + w] = chars[perm_s[w] * 20 + t] * 384;
  }

  const float* xp = dir ? xpf_b : xpf_f;
  const u16* whh = dir ? whhb : whhf;
  const float* bhh = dir ? bhh_b : bhh_f;
  u16* hout = (dir ? hb : hf) + (size_t)wg * 32 * 2560;

  const int wv = tid >> 6, ln = tid & 63, word = ln & 15, grp = ln >> 4;
  const float* xpt = xp + (wv * 4 + grp) * 12;

  // Whh' A-fragments (pre-scaled): 48 VGPRs, shared across both m-tiles
  bf16x8 Wf[3][4];
#pragma unroll
  for (int cls = 0; cls < 3; cls++) {
    int nt = cls * 8 + wv;
#pragma unroll
    for (int kt = 0; kt < 4; kt++)
      Wf[cls][kt] = *(const bf16x8*)(whh + (((nt * 4 + kt) * 64 + ln) << 3));
  }
  // bhh_n (scaled 2log2e) for this thread's 4 hids
  float4 bhn = *(const float4*)(bhh + 256 + wv * 16 + grp * 4);
  bhn.x *= 2.0f * LOG2E; bhn.y *= 2.0f * LOG2E;
  bhn.z *= 2.0f * LOG2E; bhn.w *= 2.0f * LOG2E;

  __syncthreads();  // coff_s + h_s zero ready

  const int Lmax = lens_s[31];  // sorted ascending within block

  // h_s write offsets (v8-verified mapping, + m-tile stride 4096 B)
  const int hw_off =
      (((wv >> 1) * 64) + (word | (((wv & 1) * 2 + (grp >> 1)) << 4))) * 16 +
      (grp & 1) * 8;
  // store phase: wave slot (sm = wv>>2, skt = wv&3); lane -> word sm*16+(ln&15)
  const int sm = wv >> 2, skt = wv & 3;
  const int swl = sm * 16 + word;            // block-local word
  const int sLane = lens_s[swl];
  const int hs_off = (((sm * 4 + skt) * 64 + ln) << 4);  // b128 slot, linear
  u16* hsto = hout + (size_t)swl * 2560 + skt * 32 + (grp << 3);

  char* hsb = (char*)h_s;

  float h0[4] = {0.f, 0.f, 0.f, 0.f};
  float h1[4] = {0.f, 0.f, 0.f, 0.f};

#define GSTEP(S, PAR)                                                         \
  {                                                                           \
    int off0 = coff_s[(S) * 32 + word];                                       \
    int off1 = coff_s[(S) * 32 + 16 + word];                                  \
    f32x4 x00 = *(const f32x4*)(xpt + off0);                                  \
    f32x4 x01 = *(const f32x4*)(xpt + off0 + 4);                              \
    f32x4 x02 = *(const f32x4*)(xpt + off0 + 8);                              \
    f32x4 x10 = *(const f32x4*)(xpt + off1);                                  \
    f32x4 x11 = *(const f32x4*)(xpt + off1 + 4);                              \
    f32x4 x12 = *(const f32x4*)(xpt + off1 + 8);                              \
    f32x4 a0 = (f32x4){0.f, 0.f, 0.f, 0.f};                                   \
    f32x4 a1 = (f32x4){0.f, 0.f, 0.f, 0.f};                                   \
    f32x4 a2 = (f32x4){bhn.x, bhn.y, bhn.z, bhn.w};                           \
    f32x4 b0 = (f32x4){0.f, 0.f, 0.f, 0.f};                                   \
    f32x4 b1 = (f32x4){0.f, 0.f, 0.f, 0.f};                                   \
    f32x4 b2 = (f32x4){bhn.x, bhn.y, bhn.z, bhn.w};                           \
    _Pragma("unroll")                                                         \
    for (int kt = 0; kt < 4; kt++) {                                          \
      bf16x8 Hf0 =                                                            \
          *(const bf16x8*)(hsb + (PAR) * 8192 + ((kt * 64 + ln) << 4));       \
      a0 = __builtin_amdgcn_mfma_f32_16x16x32_bf16(Wf[0][kt], Hf0, a0, 0, 0, 0); \
      a1 = __builtin_amdgcn_mfma_f32_16x16x32_bf16(Wf[1][kt], Hf0, a1, 0, 0, 0); \
      a2 = __builtin_amdgcn_mfma_f32_16x16x32_bf16(Wf[2][kt], Hf0, a2, 0, 0, 0); \
    }                                                                         \
    _Pragma("unroll")                                                         \
    for (int kt = 0; kt < 4; kt++) {                                          \
      bf16x8 Hf1 = *(const bf16x8*)(hsb + (PAR) * 8192 +                      \
                                    (((4 + kt) * 64 + ln) << 4));             \
      b0 = __builtin_amdgcn_mfma_f32_16x16x32_bf16(Wf[0][kt], Hf1, b0, 0, 0, 0); \
      b1 = __builtin_amdgcn_mfma_f32_16x16x32_bf16(Wf[1][kt], Hf1, b1, 0, 0, 0); \
      b2 = __builtin_amdgcn_mfma_f32_16x16x32_bf16(Wf[2][kt], Hf1, b2, 0, 0, 0); \
    }                                                                         \
    _Pragma("unroll")                                                         \
    for (int r = 0; r < 4; r++) {                                             \
      float rr = RCPF(1.0f + EXP2F(x00[r] + a0[r]));                          \
      float zz = RCPF(1.0f + EXP2F(x01[r] + a1[r]));                          \
      float na = fmaf(rr, a2[r], x02[r]);                                     \
      float nn = fmaf(-2.0f, RCPF(EXP2F(na) + 1.0f), 1.0f);                   \
      h0[r] = fmaf(zz, h0[r] - nn, nn);                                       \
    }                                                                         \
    {                                                                         \
      uint2 pk = make_uint2(cvtpk(h0[0], h0[1]), cvtpk(h0[2], h0[3]));        \
      *(uint2*)(hsb + ((PAR) ^ 1) * 8192 + hw_off) = pk;                      \
    }                                                                         \
    _Pragma("unroll")                                                         \
    for (int r = 0; r < 4; r++) {                                             \
      float rr = RCPF(1.0f + EXP2F(x10[r] + b0[r]));                          \
      float zz = RCPF(1.0f + EXP2F(x11[r] + b1[r]));                          \
      float na = fmaf(rr, b2[r], x12[r]);                                     \
      float nn = fmaf(-2.0f, RCPF(EXP2F(na) + 1.0f), 1.0f);                   \
      h1[r] = fmaf(zz, h1[r] - nn, nn);                                       \
    }                                                                         \
    {                                                                         \
      uint2 pk = make_uint2(cvtpk(h1[0], h1[1]), cvtpk(h1[2], h1[3]));        \
      *(uint2*)(hsb + ((PAR) ^ 1) * 8192 + 4096 + hw_off) = pk;               \
    }                                                                         \
    __syncthreads();                                                          \
    if ((S) < sLane) {                                                        \
      int tdst = dir ? (sLane - 1 - (S)) : (S);                               \
      uint4 v = *(const uint4*)(hsb + ((PAR) ^ 1) * 8192 + hs_off);           \
      *(uint4*)(hsto + tdst * 128) = v;                                       \
    }                                                                         \
  }

  for (int s = 0; s < Lmax; s += 2) {
    GSTEP(s, 0);
    if (s + 1 < Lmax) GSTEP(s + 1, 1);
  }
#undef GSTEP
}

// ---------------------------------------------------------------------------
// attn: grid nbA x 256. 16 sorted words/block, 16 threads/word (facc[16]).
// Exact v8 version (plain __syncthreads; bar_lds regressed it in v10).
// ---------------------------------------------------------------------------
__global__ __launch_bounds__(256, 2) void attn_kernel(
    const u16* __restrict__ hf, const u16* __restrict__ hb,
    const u16* __restrict__ wpf,
    const float* __restrict__ bp, const float* __restrict__ ctx,
    const int* __restrict__ perm, const int* __restrict__ lens,
    const float* __restrict__ c0p,
    float* __restrict__ out, int word_off) {
  const int blk = gridDim.x - 1 - blockIdx.x;  // longest-first
  const int lw0 = blk * 16;

  __shared__ u16 ot_s[4096];       // 8 KiB: Out_t frag layout (16x256)
  __shared__ float part_s[4][16];
  __shared__ int perm_s[16];
  __shared__ unsigned char lens_s[16];

  const int tid = threadIdx.x;
  const int wv = tid >> 6, ln = tid & 63, col = ln & 15, grp = ln >> 4;
  const int sw = tid >> 4;   // this thread's word (16 threads per word)
  const int seg = tid & 15;  // 16-dim segment of the 256-dim output

  if (tid < 16) {
    int p = perm[word_off + lw0 + tid];
    perm_s[tid] = p;
    lens_s[tid] = (unsigned char)lens[p];
  }
  __syncthreads();
  const int Lmax = lens_s[15];  // sorted ascending within block
  const int Lw = lens_s[sw];

  float bpv[2], ctxv[2];
#pragma unroll
  for (int n = 0; n < 2; n++) {
    int nt = wv + n * 4;
    bpv[n] = bp[nt * 16 + col];
    ctxv[n] = ctx[nt * 16 + col];
  }

  float facc[16];
#pragma unroll
  for (int i = 0; i < 16; i++) facc[i] = 0.f;
  float mrun = -3.0e38f, drun = 0.f;

  // seg 0..7 -> hf dims [seg*16,+16); seg 8..15 -> hb dims [(seg-8)*16,+16)
  const u16* srcbase =
      ((seg < 8) ? hf : hb) + (size_t)(lw0 + sw) * 2560 + (seg & 7) * 16;

  uint4 vn[2];
#pragma unroll
  for (int q = 0; q < 2; q++) vn[q] = *(const uint4*)(srcbase + q * 8);

  for (int t = 0; t < Lmax; t++) {
    uint4 v[2];
    v[0] = vn[0];
    v[1] = vn[1];

    // stage Out_t into frag layout: k = seg*16 + q*8
#pragma unroll
    for (int q = 0; q < 2; q++) {
      int idx = seg * 2 + q;           // k>>3, 0..31
      int kt = idx >> 2;               // k>>5
      int lane_a = sw | ((idx & 3) << 4);
      *(uint4*)(ot_s + ((kt * 64 + lane_a) << 3)) = v[q];
    }
    // prefetch next t (hidden under MFMA/score)
    if (t + 1 < Lmax) {
      const u16* src = srcbase + (t + 1) * 128;
#pragma unroll
      for (int q = 0; q < 2; q++) vn[q] = *(const uint4*)(src + q * 8);
    }
    __syncthreads();

    // proj = Out_t @ Wp^T + bp (Wp frags from L2)
    f32x4 acc[2];
#pragma unroll
    for (int n = 0; n < 2; n++) acc[n] = (f32x4){bpv[n], bpv[n], bpv[n], bpv[n]};

#pragma unroll
    for (int kt = 0; kt < 8; kt++) {
      bf16x8 Af = *(const bf16x8*)(ot_s + ((kt * 64 + ln) << 3));
#pragma unroll
      for (int n = 0; n < 2; n++) {
        int nt = wv + n * 4;
        bf16x8 Bf = *(const bf16x8*)(wpf + (((nt * 8 + kt) * 64 + ln) << 3));
        acc[n] = __builtin_amdgcn_mfma_f32_16x16x32_bf16(Af, Bf, acc[n], 0, 0, 0);
      }
    }

    // score partials: tanh(proj)*ctx summed over cols; words at (grp*4+r)
#pragma unroll
    for (int r = 0; r < 4; r++) {
      float p = fast_tanh(acc[0][r]) * ctxv[0] + fast_tanh(acc[1][r]) * ctxv[1];
      p += __shfl_xor(p, 1, 64);
      p += __shfl_xor(p, 2, 64);
      p += __shfl_xor(p, 4, 64);
      p += __shfl_xor(p, 8, 64);
      if (col == 0) part_s[wv][grp * 4 + r] = p;
    }
    __syncthreads();

    float sc = part_s[0][sw] + part_s[1][sw] + part_s[2][sw] + part_s[3][sw];

    if (t < Lw) {
      float mnew = fmaxf(mrun, sc);
      float scale = EXP2F(LOG2E * (mrun - mnew));
      float e = EXP2F(LOG2E * (sc - mnew));
      drun = drun * scale + e;
      mrun = mnew;
#pragma unroll
      for (int q = 0; q < 2; q++) {
        const u16* pv = (const u16*)&v[q];
#pragma unroll
        for (int j = 0; j < 8; j++)
          facc[q * 8 + j] = facc[q * 8 + j] * scale + e * b2f(pv[j]);
      }
    }
  }

  // reference semantics: softmax over all 20 positions; pad rows are zero
  // with constant score c0 -> denominator-only mass.
  drun += (float)(20 - Lw) * EXP2F(LOG2E * (*c0p - mrun));

  float inv = RCPF(drun);
  float* dst = out + (size_t)perm_s[sw] * 256 + seg * 16;
#pragma unroll
  for (int i = 0; i < 4; i++) {
    float4 o = make_float4(facc[i * 4] * inv, facc[i * 4 + 1] * inv,
                           facc[i * 4 + 2] * inv, facc[i * 4 + 3] * inv);
    *(float4*)(dst + i * 4) = o;
  }
}

// ---------------------------------------------------------------------------
extern "C" void kernel_launch(void* const* d_in, const int* in_sizes, int n_in,
                              void* d_out, int out_size, void* d_ws, size_t ws_size,
                              hipStream_t stream) {
  const int* chars = (const int*)d_in[0];
  const int* lens = (const int*)d_in[1];
  const float* emb = (const float*)d_in[2];
  const float* wih_f = (const float*)d_in[3];
  const float* whh_f = (const float*)d_in[4];
  const float* bih_f = (const float*)d_in[5];
  const float* bhh_f = (const float*)d_in[6];
  const float* wih_b = (const float*)d_in[7];
  const float* whh_b = (const float*)d_in[8];
  const float* bih_b = (const float*)d_in[9];
  const float* bhh_b = (const float*)d_in[10];
  const float* wp = (const float*)d_in[11];
  const float* bp = (const float*)d_in[12];
  const float* ctx = (const float*)d_in[13];
  float* outp = (float*)d_out;

  uint8_t* ws = (uint8_t*)d_ws;
  float* xpf_f = (float*)(ws + 0);            // 192 KiB (49152 f32)
  float* xpf_b = (float*)(ws + 196608);       // 192 KiB
  u16* whhf = (u16*)(ws + 393216);            // 96 KiB
  u16* whhb = (u16*)(ws + 491520);            // 96 KiB
  u16* wpf = (u16*)(ws + 589824);             // 64 KiB
  int* bins = (int*)(ws + 655360);            // 128 B
  int* offsw = (int*)(ws + 655488);           // 128 B
  float* c0p = (float*)(ws + 655616);         // 64 B
  int* permp = (int*)(ws + 655680);           // 128 KiB
  const size_t H_OFF = 1048576;

  prep_kernel<<<448, 256, 0, stream>>>(emb, wih_f, bih_f, wih_b, bih_b, bhh_f,
                                       bhh_b, whh_f, whh_b, wp, xpf_f, xpf_b,
                                       whhf, whhb, wpf);
  sort_zero<<<1, 64, 0, stream>>>(bins);
  sort_hist<<<128, 256, 0, stream>>>(lens, bins);
  sort_scan<<<1, 64, 0, stream>>>(bins, offsw, bp, ctx, c0p);
  sort_scat<<<128, 256, 0, stream>>>(lens, offsw, permp);

  const size_t per_word = 20 * 128 * 2 * 2;  // hf+hb bytes per word
  size_t avail = (ws_size > H_OFF) ? (ws_size - H_OFF) : 0;
  int maxw = (int)(avail / per_word) & ~63;
  if (maxw > 32768) maxw = 32768;
  if (maxw < 64) maxw = 64;

  for (int done = 0; done < 32768;) {
    int nw = (32768 - done < maxw) ? (32768 - done) : maxw;
    u16* hfp = (u16*)(ws + H_OFF);
    u16* hbp = hfp + (size_t)nw * 2560;
    int nbd = nw / 32;
    gru_kernel<<<2 * nbd, 512, 0, stream>>>(chars, lens, permp, xpf_f, xpf_b,
                                            whhf, whhb, bhh_f, bhh_b, hfp, hbp,
                                            done, nbd);
    attn_kernel<<<nw / 16, 256, 0, stream>>>(hfp, hbp, wpf, bp, ctx, permp,
                                             lens, c0p, outp, done);
    done += nw;
  }
}